// Round 11
// baseline (743.711 us; speedup 1.0000x reference)
//
#include <hip/hip_runtime.h>

// 2-layer GRU (B=512, T=4096, H=3) + decoder.
// 16 lanes per batch element, gate-role split, layer-pipelined, and
// TWO independent batch elements per lane (b, b+256) with interleaved
// chains: while batch A's trans ops are in flight, batch B issues.
//
//   quad0 (lanes 0-3):   L0 OWNER lanes, unit j = lane&3 (j==3 dummy)
//                        computes cz, gi, z=rcp(1+Ez), h-update; HOLDS h.
//   quad1 (lanes 4-7):   L0 AUX, unit j = 3-(lane&3): cr, gh, r, m=r*gh.
//   quad2 (8-11):        L1 OWNER (lane11 = decoder: dotA = Wdec·hb + bdec)
//   quad3 (12-15):       L1 AUX
// Trans/step: 2 exp2 + 2 rcp in shared lane slots (4-deep serial chain —
// the latency floor this round attacks via cross-batch ILP).
// Cross-lane: quad_perm bcasts; row_shr:4 (bank 0xA) owner->aux;
// row_shr:8 (bank 0xC) L0 h -> L1 lanes; row_half_mirror (bank 0x5) m->owner.

constexpr int T = 4096;
constexpr int B = 512;
constexpr float LOG2E = 1.44269504088896340736f;

__device__ __forceinline__ float fexp2(float v) { return __builtin_amdgcn_exp2f(v); }
__device__ __forceinline__ float frcp(float v)  { return __builtin_amdgcn_rcpf(v); }

template<int CTRL>
__device__ __forceinline__ float dppf(float v) {   // quad_perm broadcast, bc=1
    return __int_as_float(
        __builtin_amdgcn_update_dpp(0, __float_as_int(v), CTRL, 0xF, 0xF, true));
}
template<int CTRL, int BANK>
__device__ __forceinline__ float dppm(float oldv, float src) {  // masked move
    return __int_as_float(__builtin_amdgcn_update_dpp(
        __float_as_int(oldv), __float_as_int(src), CTRL, 0xF, BANK, false));
}

// One pipeline iteration on hidden-state variable H. MODE: 0 normal,
// 1 first (freeze L1), 2 last (freeze L0). YV = y(i-2) on lane g16==11.
#define GRU_IT(MODE, H, X0, X1, X2, YV) do {                                   \
    float hb0 = dppf<0x00>(H), hb1 = dppf<0x55>(H), hb2 = dppf<0xAA>(H);       \
    hb0 = dppm<0x114, 0xA>(hb0, hb0);   /* aux quads <- owner hb */            \
    hb1 = dppm<0x114, 0xA>(hb1, hb1);                                          \
    hb2 = dppm<0x114, 0xA>(hb2, hb2);                                          \
    float s0 = dppm<0x118, 0xC>((X0), hb0);  /* L1 lanes <- L0 hb */           \
    float s1 = dppm<0x118, 0xC>((X1), hb1);                                    \
    float s2 = dppm<0x118, 0xC>((X2), hb2);                                    \
    float cx  = fmaf(uA2, s2, fmaf(uA1, s1, fmaf(uA0, s0, bA)));               \
    float chh = fmaf(vA2, hb2, fmaf(vA1, hb1, vA0 * hb0));                     \
    float c   = cx + chh;            /* owner: cz; aux: cr; lane11: y */       \
    YV = c;                                                                    \
    float gx  = fmaf(uB2, s2, fmaf(uB1, s1, fmaf(uB0, s0, bB)));               \
    float ghh = fmaf(vB2, hb2, fmaf(vB1, hb1, vB0 * hb0));                     \
    float g   = gx + ghh;            /* owner: gi_s; aux: gh_s */              \
    float E   = fexp2(c);            /* owner: Ez;  aux: Er */                 \
    float w   = frcp(1.0f + E);      /* owner: z;   aux: r  */                 \
    float m   = w * g;               /* aux: r*gh_s */                         \
    float mm  = dppm<0x141, 0x5>(m, m);  /* owner <- mirrored aux partner */   \
    float aa  = mm + g;              /* owner: r*gh_s + gi_s */                \
    float F   = fexp2(aa);                                                     \
    float nn  = fmaf(-2.0f, frcp(F + 1.0f), 1.0f);   /* tanh */                \
    float hn  = fmaf(w, H - nn, nn); /* z*(h-n)+n */                           \
    if ((MODE) == 0)      H = hn;                                              \
    else if ((MODE) == 1) H = is_L0 ? hn : H;                                  \
    else                  H = is_L0 ? H : hn;                                  \
} while (0)

__global__ __launch_bounds__(64, 1)
void gru_pipe(const float* __restrict__ x,     // [B,T,3]
              const float* __restrict__ h0,    // [2,B,3]
              const float* __restrict__ Wih,   // [2,9,3]
              const float* __restrict__ Whh,   // [2,9,3]
              const float* __restrict__ bih,   // [2,9]
              const float* __restrict__ bhh,   // [2,9]
              const float* __restrict__ Wdec,  // [1,3]
              const float* __restrict__ bdec,  // [1]
              float* __restrict__ out)         // y[B*T] then h_out[2*B*3]
{
    const int lane  = threadIdx.x;             // 0..63, block = 1 wave
    const int g16   = lane & 15;
    const int quad  = g16 >> 2;                // 0..3
    const int layer = quad >> 1;
    const bool ownr = (quad & 1) == 0;
    const int kk    = g16 & 3;
    const bool isdec = (g16 == 11);
    const bool is_L0 = (g16 < 8);
    const bool dlane = isdec;
    const int bA_ = (blockIdx.x * 64 + lane) >> 4;    // batch A (0..255)
    const int bB_ = bA_ + 256;                        // batch B

    // unit index: owner lane kk -> unit kk; aux lane kk -> unit 3-kk (mirror)
    const int  uj    = ownr ? (kk < 3 ? kk : 0) : (kk > 0 ? 3 - kk : 0);
    const bool valid = ownr ? (kk < 3) : (kk > 0);
    const float zm = valid ? 1.0f : 0.0f;
    const float sR = -LOG2E * zm;              // r/z chains carry -log2(e)
    const float sN = 2.0f * LOG2E * zm;        // n chain carries 2*log2(e)

    const float* Wi = Wih + layer * 27;
    const float* Wh = Whh + layer * 27;
    const float* bi = bih + layer * 9;
    const float* bh = bhh + layer * 9;

    // dotA: owner -> z-gate row (3+uj); aux -> r-gate row (uj)
    const int rA = ownr ? (3 + uj) : uj;
    float uA0 = Wi[rA*3+0]*sR, uA1 = Wi[rA*3+1]*sR, uA2 = Wi[rA*3+2]*sR;
    float vA0 = Wh[rA*3+0]*sR, vA1 = Wh[rA*3+1]*sR, vA2 = Wh[rA*3+2]*sR;
    float bA  = (bi[rA] + bh[rA]) * sR;
    // dotB: owner -> gi (x-side of n row); aux -> gh (h-side of n row)
    const int rN = 6 + uj;
    float uB0, uB1, uB2, vB0, vB1, vB2, bB;
    if (ownr) {
        uB0 = Wi[rN*3+0]*sN; uB1 = Wi[rN*3+1]*sN; uB2 = Wi[rN*3+2]*sN;
        vB0 = 0.0f; vB1 = 0.0f; vB2 = 0.0f;
        bB  = bi[rN]*sN;
    } else {
        uB0 = 0.0f; uB1 = 0.0f; uB2 = 0.0f;
        vB0 = Wh[rN*3+0]*sN; vB1 = Wh[rN*3+1]*sN; vB2 = Wh[rN*3+2]*sN;
        bB  = bh[rN]*sN;
    }
    if (isdec) {   // lane11: dotA = decoder (reads L1 hb); dotB already zeroed
        uA0 = uA1 = uA2 = 0.0f;
        vA0 = Wdec[0]; vA1 = Wdec[1]; vA2 = Wdec[2];
        bA  = bdec[0];
    }

    float hA = (ownr && kk < 3) ? h0[layer * B * 3 + bA_ * 3 + kk] : 0.0f;
    float hB = (ownr && kk < 3) ? h0[layer * B * 3 + bB_ * 3 + kk] : 0.0f;

    const float4* xbA = reinterpret_cast<const float4*>(x + (size_t)bA_ * T * 3);
    const float4* xbB = reinterpret_cast<const float4*>(x + (size_t)bB_ * T * 3);
    float* yoA = out + (size_t)bA_ * T;
    float* yoB = out + (size_t)bB_ * T;

    // double-buffered chunk registers per batch: cu = chunk t, nx = chunk t+1
    float4 nA0 = xbA[0], nA1 = xbA[1], nA2 = xbA[2];
    float4 cA0 = xbA[3], cA1 = xbA[4], cA2 = xbA[5];
    float4 nB0 = xbB[0], nB1 = xbB[1], nB2 = xbB[2];
    float4 cB0 = xbB[3], cB1 = xbB[4], cB2 = xbB[5];
    float y0A, y1A, y2A, y3A, p2A, p3A;
    float y0B, y1B, y2B, y3B, p2B, p3B;

    // ---- chunk 0 (prologue: freeze L1 h at i=0) ----
    {
        GRU_IT(1, hA, nA0.x, nA0.y, nA0.z, y0A);
        GRU_IT(1, hB, nB0.x, nB0.y, nB0.z, y0B);
        GRU_IT(0, hA, nA0.w, nA1.x, nA1.y, y1A);
        GRU_IT(0, hB, nB0.w, nB1.x, nB1.y, y1B);
        GRU_IT(0, hA, nA1.z, nA1.w, nA2.x, y2A);
        GRU_IT(0, hB, nB1.z, nB1.w, nB2.x, y2B);
        GRU_IT(0, hA, nA2.y, nA2.z, nA2.w, y3A);
        GRU_IT(0, hB, nB2.y, nB2.z, nB2.w, y3B);
        p2A = y2A; p3A = y3A;                 // carry y(0), y(1)
        p2B = y2B; p3B = y3B;
    }
    nA0 = xbA[6]; nA1 = xbA[7]; nA2 = xbA[8];    // chunk 2
    nB0 = xbB[6]; nB1 = xbB[7]; nB2 = xbB[8];
    // invariant entering loop (tc=1): cu = d(1), nx = d(2)

    #pragma unroll 1
    for (int tc = 1; tc <= 1021; tc += 2) {
        // entry: cu = d(tc), nx = d(tc+1)
        const float4* pfa = xbA + (tc + 2) * 3;              // d(tc+2), in-bounds
        const float4* pfb = xbB + (tc + 2) * 3;
        float4 LA0 = pfa[0], LA1 = pfa[1], LA2 = pfa[2];
        float4 LB0 = pfb[0], LB1 = pfb[1], LB2 = pfb[2];
        // ---- chunk tc (from cu), chains interleaved ----
        GRU_IT(0, hA, cA0.x, cA0.y, cA0.z, y0A);
        GRU_IT(0, hB, cB0.x, cB0.y, cB0.z, y0B);
        GRU_IT(0, hA, cA0.w, cA1.x, cA1.y, y1A);
        GRU_IT(0, hB, cB0.w, cB1.x, cB1.y, y1B);
        GRU_IT(0, hA, cA1.z, cA1.w, cA2.x, y2A);
        GRU_IT(0, hB, cB1.z, cB1.w, cB2.x, y2B);
        GRU_IT(0, hA, cA2.y, cA2.z, cA2.w, y3A);
        GRU_IT(0, hB, cB2.y, cB2.z, cB2.w, y3B);
        if (dlane) {
            float4 q;
            q.x = p2A; q.y = p3A; q.z = y0A; q.w = y1A;
            *(float4*)(yoA + 4 * tc - 4) = q;                // yA(4tc-4..4tc-1)
            q.x = p2B; q.y = p3B; q.z = y0B; q.w = y1B;
            *(float4*)(yoB + 4 * tc - 4) = q;
        }
        p2A = y2A; p3A = y3A; p2B = y2B; p3B = y3B;
        const float4* pga = xbA + (((tc + 3) & 1023) * 3);   // d(tc+3), masked
        const float4* pgb = xbB + (((tc + 3) & 1023) * 3);
        float4 MA0 = pga[0], MA1 = pga[1], MA2 = pga[2];
        float4 MB0 = pgb[0], MB1 = pgb[1], MB2 = pgb[2];
        // ---- chunk tc+1 (from nx) ----
        GRU_IT(0, hA, nA0.x, nA0.y, nA0.z, y0A);
        GRU_IT(0, hB, nB0.x, nB0.y, nB0.z, y0B);
        GRU_IT(0, hA, nA0.w, nA1.x, nA1.y, y1A);
        GRU_IT(0, hB, nB0.w, nB1.x, nB1.y, y1B);
        GRU_IT(0, hA, nA1.z, nA1.w, nA2.x, y2A);
        GRU_IT(0, hB, nB1.z, nB1.w, nB2.x, y2B);
        GRU_IT(0, hA, nA2.y, nA2.z, nA2.w, y3A);
        GRU_IT(0, hB, nB2.y, nB2.z, nB2.w, y3B);
        if (dlane) {
            float4 q;
            q.x = p2A; q.y = p3A; q.z = y0A; q.w = y1A;
            *(float4*)(yoA + 4 * tc) = q;                    // yA(4tc..4tc+3)
            q.x = p2B; q.y = p3B; q.z = y0B; q.w = y1B;
            *(float4*)(yoB + 4 * tc) = q;
        }
        p2A = y2A; p3A = y3A; p2B = y2B; p3B = y3B;
        cA0 = LA0; cA1 = LA1; cA2 = LA2;                     // d(tc+2)
        cB0 = LB0; cB1 = LB1; cB2 = LB2;
        nA0 = MA0; nA1 = MA1; nA2 = MA2;                     // d(tc+3)
        nB0 = MB0; nB1 = MB1; nB2 = MB2;
    }
    // exit: cu = d(1023), nx = wrapped (unused)

    // ---- chunk 1023 ----
    GRU_IT(0, hA, cA0.x, cA0.y, cA0.z, y0A);
    GRU_IT(0, hB, cB0.x, cB0.y, cB0.z, y0B);
    GRU_IT(0, hA, cA0.w, cA1.x, cA1.y, y1A);
    GRU_IT(0, hB, cB0.w, cB1.x, cB1.y, y1B);
    GRU_IT(0, hA, cA1.z, cA1.w, cA2.x, y2A);
    GRU_IT(0, hB, cB1.z, cB1.w, cB2.x, y2B);
    GRU_IT(0, hA, cA2.y, cA2.z, cA2.w, y3A);
    GRU_IT(0, hB, cB2.y, cB2.z, cB2.w, y3B);
    if (dlane) {
        float4 q;
        q.x = p2A; q.y = p3A; q.z = y0A; q.w = y1A;
        *(float4*)(yoA + 4088) = q;                          // y(4088..4091)
        q.x = p2B; q.y = p3B; q.z = y0B; q.w = y1B;
        *(float4*)(yoB + 4088) = q;
    }
    p2A = y2A; p3A = y3A; p2B = y2B; p3B = y3B;              // y(4092), y(4093)

    // ---- epilogue ----
    GRU_IT(2, hA, 0.0f, 0.0f, 0.0f, y0A);   // i=T: L1 finishes h1(T-1); y(T-2)
    GRU_IT(2, hB, 0.0f, 0.0f, 0.0f, y0B);
    {
        float b0 = dppf<0x00>(hA), b1 = dppf<0x55>(hA), b2 = dppf<0xAA>(hA);
        y1A = fmaf(vA2, b2, fmaf(vA1, b1, fmaf(vA0, b0, bA)));  // lane11: y(T-1)
        b0 = dppf<0x00>(hB); b1 = dppf<0x55>(hB); b2 = dppf<0xAA>(hB);
        y1B = fmaf(vA2, b2, fmaf(vA1, b1, fmaf(vA0, b0, bA)));
    }
    if (dlane) {
        float4 q;
        q.x = p2A; q.y = p3A; q.z = y0A; q.w = y1A;
        *(float4*)(yoA + 4092) = q;                          // y(4092..4095)
        q.x = p2B; q.y = p3B; q.z = y0B; q.w = y1B;
        *(float4*)(yoB + 4092) = q;
    }

    // final hidden states (owner lanes hold h)
    if (ownr && kk < 3) {
        out[B * T + (layer * B + bA_) * 3 + kk] = hA;
        out[B * T + (layer * B + bB_) * 3 + kk] = hB;
    }
}

extern "C" void kernel_launch(void* const* d_in, const int* in_sizes, int n_in,
                              void* d_out, int out_size, void* d_ws, size_t ws_size,
                              hipStream_t stream) {
    const float* x    = (const float*)d_in[0];
    const float* h0   = (const float*)d_in[1];
    const float* Wih  = (const float*)d_in[2];
    const float* Whh  = (const float*)d_in[3];
    const float* bih  = (const float*)d_in[4];
    const float* bhh  = (const float*)d_in[5];
    const float* Wdec = (const float*)d_in[6];
    const float* bdec = (const float*)d_in[7];
    float* out = (float*)d_out;

    gru_pipe<<<(B / 2 * 16) / 64, 64, 0, stream>>>(x, h0, Wih, Whh, bih, bhh,
                                                   Wdec, bdec, out);
}